// Round 2
// baseline (184.917 us; speedup 1.0000x reference)
//
#include <hip/hip_runtime.h>

typedef float f4 __attribute__((ext_vector_type(4)));
typedef int   i4 __attribute__((ext_vector_type(4)));

#define NOBJ 64
#define PPT  8   // points per thread

__global__ __launch_bounds__(256) void compose_kernel(
    const float* __restrict__ trans,    // [NOBJ,3]
    const float* __restrict__ rotors,   // [NOBJ,4]
    const float* __restrict__ means,    // [M,3]
    const float* __restrict__ quats,    // [M,4]
    const int*   __restrict__ indices,  // [M]
    float* __restrict__ out,            // [M*3] means ++ [M*4] quats
    int M)
{
    // SoA object table: rw rx ry rz tx ty tz. 64 floats per row = 2 banks'
    // worth per entry-class -> any random gather is <=2-way (free).
    __shared__ float s_tab[7][NOBJ];
    const int tid = threadIdx.x;
    if (tid < NOBJ) {
        f4 r = ((const f4*)rotors)[tid];
        s_tab[0][tid] = r.x;
        s_tab[1][tid] = r.y;
        s_tab[2][tid] = r.z;
        s_tab[3][tid] = r.w;
        s_tab[4][tid] = trans[tid * 3 + 0];
        s_tab[5][tid] = trans[tid * 3 + 1];
        s_tab[6][tid] = trans[tid * 3 + 2];
    }
    __syncthreads();

    float* out_means = out;
    float* out_quats = out + (size_t)M * 3;

    const int ngroups = M >> 3;                   // 8 points at a time
    const int gstride = gridDim.x * blockDim.x;

    for (int t = blockIdx.x * blockDim.x + tid; t < ngroups; t += gstride) {
        // Issue ALL global loads up front (independent -> max MLP):
        f4 mv[6];
#pragma unroll
        for (int k = 0; k < 6; ++k) mv[k] = ((const f4*)means)[t * 6 + k];
        f4 qv[8];
#pragma unroll
        for (int k = 0; k < 8; ++k) qv[k] = ((const f4*)quats)[t * 8 + k];
        i4 ia = ((const i4*)indices)[t * 2 + 0];
        i4 ib = ((const i4*)indices)[t * 2 + 1];

        f4 sm[6];
        f4 sq[8];

#pragma unroll
        for (int p = 0; p < 8; ++p) {
            const int id = (p < 4) ? ia[p] : ib[p - 4];   // p is unroll-const
            const float rw = s_tab[0][id];
            const float rx = s_tab[1][id];
            const float ry = s_tab[2][id];
            const float rz = s_tab[3][id];
            const float tx = s_tab[4][id];
            const float ty = s_tab[5][id];
            const float tz = s_tab[6][id];

            const float vx = mv[(3 * p + 0) >> 2][(3 * p + 0) & 3];
            const float vy = mv[(3 * p + 1) >> 2][(3 * p + 1) & 3];
            const float vz = mv[(3 * p + 2) >> 2][(3 * p + 2) & 3];

            // quat_rotate: t2 = 2*cross(r.xyz, v); o = v + w*t2 + cross(r.xyz, t2) + trans
            const float t2x = 2.0f * (ry * vz - rz * vy);
            const float t2y = 2.0f * (rz * vx - rx * vz);
            const float t2z = 2.0f * (rx * vy - ry * vx);
            sm[(3 * p + 0) >> 2][(3 * p + 0) & 3] = vx + rw * t2x + (ry * t2z - rz * t2y) + tx;
            sm[(3 * p + 1) >> 2][(3 * p + 1) & 3] = vy + rw * t2y + (rz * t2x - rx * t2z) + ty;
            sm[(3 * p + 2) >> 2][(3 * p + 2) & 3] = vz + rw * t2z + (rx * t2y - ry * t2x) + tz;

            // quat_mul(r, q)
            const float bw = qv[p].x, bx = qv[p].y, by = qv[p].z, bz = qv[p].w;
            f4 o;
            o.x = rw * bw - rx * bx - ry * by - rz * bz;
            o.y = rw * bx + rx * bw + ry * bz - rz * by;
            o.z = rw * by - rx * bz + ry * bw + rz * bx;
            o.w = rw * bz + rx * by - ry * bx + rz * bw;
            sq[p] = o;
        }

        // Nontemporal stores: don't evict the streaming inputs from L2/L3.
#pragma unroll
        for (int k = 0; k < 6; ++k)
            __builtin_nontemporal_store(sm[k], &((f4*)out_means)[t * 6 + k]);
#pragma unroll
        for (int k = 0; k < 8; ++k)
            __builtin_nontemporal_store(sq[k], &((f4*)out_quats)[t * 8 + k]);
    }

    // Tail (M % 8 != 0) — scalar path, first threads of the grid.
    const int tail = M & 7;
    if (tail) {
        const int g = blockIdx.x * blockDim.x + tid;
        if (g < tail) {
            const int i  = (M >> 3) * 8 + g;
            const int id = indices[i];
            const float rw = s_tab[0][id], rx = s_tab[1][id];
            const float ry = s_tab[2][id], rz = s_tab[3][id];
            const float vx_ = means[i * 3 + 0];
            const float vy_ = means[i * 3 + 1];
            const float vz_ = means[i * 3 + 2];
            const float t2x = 2.0f * (ry * vz_ - rz * vy_);
            const float t2y = 2.0f * (rz * vx_ - rx * vz_);
            const float t2z = 2.0f * (rx * vy_ - ry * vx_);
            out_means[i * 3 + 0] = vx_ + rw * t2x + (ry * t2z - rz * t2y) + s_tab[4][id];
            out_means[i * 3 + 1] = vy_ + rw * t2y + (rz * t2x - rx * t2z) + s_tab[5][id];
            out_means[i * 3 + 2] = vz_ + rw * t2z + (rx * t2y - ry * t2x) + s_tab[6][id];
            const float bw = quats[i * 4 + 0], bx = quats[i * 4 + 1];
            const float by = quats[i * 4 + 2], bz = quats[i * 4 + 3];
            out_quats[i * 4 + 0] = rw * bw - rx * bx - ry * by - rz * bz;
            out_quats[i * 4 + 1] = rw * bx + rx * bw + ry * bz - rz * by;
            out_quats[i * 4 + 2] = rw * by - rx * bz + ry * bw + rz * bx;
            out_quats[i * 4 + 3] = rw * bz + rx * by - ry * bx + rz * bw;
        }
    }
}

extern "C" void kernel_launch(void* const* d_in, const int* in_sizes, int n_in,
                              void* d_out, int out_size, void* d_ws, size_t ws_size,
                              hipStream_t stream) {
    const float* trans   = (const float*)d_in[0];
    const float* rotors  = (const float*)d_in[1];
    const float* means   = (const float*)d_in[2];
    const float* quats   = (const float*)d_in[3];
    const int*   indices = (const int*)d_in[4];
    const int M = in_sizes[4];
    float* out = (float*)d_out;

    const int threads = 256;
    int ngroups = M >> 3;
    if (ngroups < 1) ngroups = 1;
    int blocks = (ngroups + threads - 1) / threads;

    compose_kernel<<<blocks, threads, 0, stream>>>(trans, rotors, means, quats,
                                                   indices, out, M);
}

// Round 3
// 41.607 us; speedup vs baseline: 4.4444x; 4.4444x over previous
//
#include <hip/hip_runtime.h>

typedef float f4 __attribute__((ext_vector_type(4)));

#define NOBJ 64
#define THR  256
#define PTS  1024   // points per block (4 per thread)

__global__ __launch_bounds__(THR) void compose_kernel(
    const float* __restrict__ trans,    // [NOBJ,3]
    const float* __restrict__ rotors,   // [NOBJ,4]
    const float* __restrict__ means,    // [M,3]
    const float* __restrict__ quats,    // [M,4]
    const int*   __restrict__ indices,  // [M]
    float* __restrict__ out,            // [M*3] means ++ [M*4] quats
    int M)
{
    __shared__ float s_tab[7][NOBJ];   // SoA: rw rx ry rz tx ty tz
    __shared__ float s_m[PTS * 3];     // 12 KB means staging (linear)

    const int tid  = threadIdx.x;
    const int base = blockIdx.x * PTS;            // first point of this block
    const int mf4_lim  = (3 * M) >> 2;            // total f4's in means (M%4==0 here)
    const int mbase_f4 = (base * 3) >> 2;         // base*3 divisible by 4 (base%1024==0)

    // ---- Phase 0: issue independent global loads --------------------------
    // quats + indices for my 4 points (coalesced: lane-contiguous per k)
    f4  qv[4];
    int idv[4];
#pragma unroll
    for (int k = 0; k < 4; ++k) {
        const int p = base + k * THR + tid;
        if (p < M) {
            qv[k]  = ((const f4*)quats)[p];
            idv[k] = indices[p];
        } else { qv[k] = (f4){0,0,0,0}; idv[k] = 0; }
    }
    // means: 3 coalesced f4 per thread -> LDS (linear f4 layout)
#pragma unroll
    for (int k = 0; k < 3; ++k) {
        const int gi = mbase_f4 + k * THR + tid;
        if (gi < mf4_lim)
            ((f4*)s_m)[k * THR + tid] = ((const f4*)means)[gi];
    }
    // object table (SoA)
    if (tid < NOBJ) {
        f4 r = ((const f4*)rotors)[tid];
        s_tab[0][tid] = r.x;
        s_tab[1][tid] = r.y;
        s_tab[2][tid] = r.z;
        s_tab[3][tid] = r.w;
        s_tab[4][tid] = trans[tid * 3 + 0];
        s_tab[5][tid] = trans[tid * 3 + 1];
        s_tab[6][tid] = trans[tid * 3 + 2];
    }
    __syncthreads();

    float* out_means = out;
    float* out_quats = out + (size_t)M * 3;

    // ---- Phase 2: compute (means via LDS stride-3 reads: 2-way = free) ----
#pragma unroll
    for (int k = 0; k < 4; ++k) {
        const int p  = base + k * THR + tid;
        if (p >= M) continue;
        const int lp = k * THR + tid;             // local point index

        const float vx = s_m[lp * 3 + 0];
        const float vy = s_m[lp * 3 + 1];
        const float vz = s_m[lp * 3 + 2];

        const int id = idv[k];
        const float rw = s_tab[0][id];
        const float rx = s_tab[1][id];
        const float ry = s_tab[2][id];
        const float rz = s_tab[3][id];

        // quat_rotate + translate
        const float t2x = 2.0f * (ry * vz - rz * vy);
        const float t2y = 2.0f * (rz * vx - rx * vz);
        const float t2z = 2.0f * (rx * vy - ry * vx);
        const float omx = vx + rw * t2x + (ry * t2z - rz * t2y) + s_tab[4][id];
        const float omy = vy + rw * t2y + (rz * t2x - rx * t2z) + s_tab[5][id];
        const float omz = vz + rw * t2z + (rx * t2y - ry * t2x) + s_tab[6][id];

        // write result means back to LDS (same slots, own thread -> no race)
        s_m[lp * 3 + 0] = omx;
        s_m[lp * 3 + 1] = omy;
        s_m[lp * 3 + 2] = omz;

        // quat_mul(r, q) -> direct coalesced store
        const float bw = qv[k].x, bx = qv[k].y, by = qv[k].z, bz = qv[k].w;
        f4 o;
        o.x = rw * bw - rx * bx - ry * by - rz * bz;
        o.y = rw * bx + rx * bw + ry * bz - rz * by;
        o.z = rw * by - rx * bz + ry * bw + rz * bx;
        o.w = rw * bz + rx * by - ry * bx + rz * bw;
        ((f4*)out_quats)[p] = o;
    }
    __syncthreads();

    // ---- Phase 3: coalesced means store out -------------------------------
#pragma unroll
    for (int k = 0; k < 3; ++k) {
        const int gi = mbase_f4 + k * THR + tid;
        if (gi < mf4_lim)
            ((f4*)out_means)[gi] = ((const f4*)s_m)[k * THR + tid];
    }
}

extern "C" void kernel_launch(void* const* d_in, const int* in_sizes, int n_in,
                              void* d_out, int out_size, void* d_ws, size_t ws_size,
                              hipStream_t stream) {
    const float* trans   = (const float*)d_in[0];
    const float* rotors  = (const float*)d_in[1];
    const float* means   = (const float*)d_in[2];
    const float* quats   = (const float*)d_in[3];
    const int*   indices = (const int*)d_in[4];
    const int M = in_sizes[4];
    float* out = (float*)d_out;

    const int blocks = (M + PTS - 1) / PTS;
    compose_kernel<<<blocks, THR, 0, stream>>>(trans, rotors, means, quats,
                                               indices, out, M);
}

// Round 4
// 40.466 us; speedup vs baseline: 4.5697x; 1.0282x over previous
//
#include <hip/hip_runtime.h>

typedef float f4 __attribute__((ext_vector_type(4)));

#define NOBJ 64
#define THR  256
#define PTS  1024   // points per tile (4 per thread)

__global__ __launch_bounds__(THR) void compose_kernel(
    const float* __restrict__ trans,    // [NOBJ,3]
    const float* __restrict__ rotors,   // [NOBJ,4]
    const float* __restrict__ means,    // [M,3]
    const float* __restrict__ quats,    // [M,4]
    const int*   __restrict__ indices,  // [M]
    float* __restrict__ out,            // [M*3] means ++ [M*4] quats
    int M, int ntiles)
{
    __shared__ float s_tab[7][NOBJ];   // SoA: rw rx ry rz tx ty tz
    __shared__ float s_m[PTS * 3];     // 12 KB means staging (linear)

    const int tid = threadIdx.x;

    // Object table: loaded ONCE per (persistent) block.
    if (tid < NOBJ) {
        f4 r = ((const f4*)rotors)[tid];
        s_tab[0][tid] = r.x;
        s_tab[1][tid] = r.y;
        s_tab[2][tid] = r.z;
        s_tab[3][tid] = r.w;
        s_tab[4][tid] = trans[tid * 3 + 0];
        s_tab[5][tid] = trans[tid * 3 + 1];
        s_tab[6][tid] = trans[tid * 3 + 2];
    }

    float* out_means = out;
    float* out_quats = out + (size_t)M * 3;
    const int mf4_lim = (3 * M) >> 2;             // f4 count in means (M%4==0)

    for (int tile = blockIdx.x; tile < ntiles; tile += gridDim.x) {
        const int base     = tile * PTS;
        const int mbase_f4 = (base * 3) >> 2;     // base%1024==0 -> divisible

        // ---- Phase 0: issue independent global loads ----------------------
        f4  qv[4];
        int idv[4];
#pragma unroll
        for (int k = 0; k < 4; ++k) {
            const int p = base + k * THR + tid;
            if (p < M) {
                qv[k]  = ((const f4*)quats)[p];
                idv[k] = indices[p];
            } else { qv[k] = (f4){0,0,0,0}; idv[k] = 0; }
        }
        f4 mstage[3];
#pragma unroll
        for (int k = 0; k < 3; ++k) {
            const int gi = mbase_f4 + k * THR + tid;
            mstage[k] = (gi < mf4_lim) ? ((const f4*)means)[gi] : (f4){0,0,0,0};
        }
        __syncthreads();   // s_m free for reuse (covers first-iter s_tab too)
#pragma unroll
        for (int k = 0; k < 3; ++k)
            ((f4*)s_m)[k * THR + tid] = mstage[k];
        __syncthreads();

        // ---- Phase 1: compute (LDS stride-3 reads: 2-way = free) ----------
#pragma unroll
        for (int k = 0; k < 4; ++k) {
            const int p  = base + k * THR + tid;
            if (p >= M) continue;
            const int lp = k * THR + tid;

            const float vx = s_m[lp * 3 + 0];
            const float vy = s_m[lp * 3 + 1];
            const float vz = s_m[lp * 3 + 2];

            const int id = idv[k];
            const float rw = s_tab[0][id];
            const float rx = s_tab[1][id];
            const float ry = s_tab[2][id];
            const float rz = s_tab[3][id];

            const float t2x = 2.0f * (ry * vz - rz * vy);
            const float t2y = 2.0f * (rz * vx - rx * vz);
            const float t2z = 2.0f * (rx * vy - ry * vx);
            const float omx = vx + rw * t2x + (ry * t2z - rz * t2y) + s_tab[4][id];
            const float omy = vy + rw * t2y + (rz * t2x - rx * t2z) + s_tab[5][id];
            const float omz = vz + rw * t2z + (rx * t2y - ry * t2x) + s_tab[6][id];

            s_m[lp * 3 + 0] = omx;
            s_m[lp * 3 + 1] = omy;
            s_m[lp * 3 + 2] = omz;

            const float bw = qv[k].x, bx = qv[k].y, by = qv[k].z, bz = qv[k].w;
            f4 o;
            o.x = rw * bw - rx * bx - ry * by - rz * bz;
            o.y = rw * bx + rx * bw + ry * bz - rz * by;
            o.z = rw * by - rx * bz + ry * bw + rz * bx;
            o.w = rw * bz + rx * by - ry * bx + rz * bw;
            __builtin_nontemporal_store(o, &((f4*)out_quats)[p]);
        }
        __syncthreads();

        // ---- Phase 2: coalesced means store (nt: don't evict L3 inputs) ---
#pragma unroll
        for (int k = 0; k < 3; ++k) {
            const int gi = mbase_f4 + k * THR + tid;
            if (gi < mf4_lim)
                __builtin_nontemporal_store(((const f4*)s_m)[k * THR + tid],
                                            &((f4*)out_means)[gi]);
        }
    }
}

extern "C" void kernel_launch(void* const* d_in, const int* in_sizes, int n_in,
                              void* d_out, int out_size, void* d_ws, size_t ws_size,
                              hipStream_t stream) {
    const float* trans   = (const float*)d_in[0];
    const float* rotors  = (const float*)d_in[1];
    const float* means   = (const float*)d_in[2];
    const float* quats   = (const float*)d_in[3];
    const int*   indices = (const int*)d_in[4];
    const int M = in_sizes[4];
    float* out = (float*)d_out;

    const int ntiles = (M + PTS - 1) / PTS;
    int blocks = ntiles < 2048 ? ntiles : 2048;   // persistent: 8 blocks/CU
    compose_kernel<<<blocks, THR, 0, stream>>>(trans, rotors, means, quats,
                                               indices, out, M, ntiles);
}

// Round 5
// 40.225 us; speedup vs baseline: 4.5970x; 1.0060x over previous
//
#include <hip/hip_runtime.h>

typedef float f4 __attribute__((ext_vector_type(4)));

#define NOBJ 64
#define THR  256
#define PTS  2048   // points per tile (8 per thread)

__global__ __launch_bounds__(THR) void compose_kernel(
    const float* __restrict__ trans,    // [NOBJ,3]
    const float* __restrict__ rotors,   // [NOBJ,4]
    const float* __restrict__ means,    // [M,3]
    const float* __restrict__ quats,    // [M,4]
    const int*   __restrict__ indices,  // [M]
    float* __restrict__ out,            // [M*3] means ++ [M*4] quats
    int M, int ntiles)
{
    __shared__ float s_tab[7][NOBJ];   // SoA: rw rx ry rz tx ty tz
    __shared__ float s_m[PTS * 3];     // 24 KB means staging (linear)

    const int tid = threadIdx.x;

    // Object table: loaded once per (persistent) block.
    if (tid < NOBJ) {
        f4 r = ((const f4*)rotors)[tid];
        s_tab[0][tid] = r.x;
        s_tab[1][tid] = r.y;
        s_tab[2][tid] = r.z;
        s_tab[3][tid] = r.w;
        s_tab[4][tid] = trans[tid * 3 + 0];
        s_tab[5][tid] = trans[tid * 3 + 1];
        s_tab[6][tid] = trans[tid * 3 + 2];
    }

    float* out_means = out;
    float* out_quats = out + (size_t)M * 3;
    const int mf4_lim = (3 * M) >> 2;             // f4 count in means (M%4==0)

    for (int tile = blockIdx.x; tile < ntiles; tile += gridDim.x) {
        const int base     = tile * PTS;
        const int mbase_f4 = (base * 3) >> 2;     // base%2048==0 -> divisible

        // ---- Phase 0: issue ALL independent global loads ------------------
        f4  qv[8];
        int idv[8];
#pragma unroll
        for (int k = 0; k < 8; ++k) {
            const int p = base + k * THR + tid;
            if (p < M) {
                qv[k]  = ((const f4*)quats)[p];
                idv[k] = indices[p];
            } else { qv[k] = (f4){0,0,0,0}; idv[k] = 0; }
        }
        f4 mstage[6];
#pragma unroll
        for (int k = 0; k < 6; ++k) {
            const int gi = mbase_f4 + k * THR + tid;
            mstage[k] = (gi < mf4_lim) ? ((const f4*)means)[gi] : (f4){0,0,0,0};
        }
        __syncthreads();   // s_m free for reuse (covers first-iter s_tab too)
#pragma unroll
        for (int k = 0; k < 6; ++k)
            ((f4*)s_m)[k * THR + tid] = mstage[k];
        __syncthreads();

        // ---- Phase 1: compute (LDS stride-3 reads: 2-way = free) ----------
#pragma unroll
        for (int k = 0; k < 8; ++k) {
            const int p  = base + k * THR + tid;
            if (p >= M) continue;
            const int lp = k * THR + tid;

            const float vx = s_m[lp * 3 + 0];
            const float vy = s_m[lp * 3 + 1];
            const float vz = s_m[lp * 3 + 2];

            const int id = idv[k];
            const float rw = s_tab[0][id];
            const float rx = s_tab[1][id];
            const float ry = s_tab[2][id];
            const float rz = s_tab[3][id];

            const float t2x = 2.0f * (ry * vz - rz * vy);
            const float t2y = 2.0f * (rz * vx - rx * vz);
            const float t2z = 2.0f * (rx * vy - ry * vx);
            const float omx = vx + rw * t2x + (ry * t2z - rz * t2y) + s_tab[4][id];
            const float omy = vy + rw * t2y + (rz * t2x - rx * t2z) + s_tab[5][id];
            const float omz = vz + rw * t2z + (rx * t2y - ry * t2x) + s_tab[6][id];

            s_m[lp * 3 + 0] = omx;
            s_m[lp * 3 + 1] = omy;
            s_m[lp * 3 + 2] = omz;

            const float bw = qv[k].x, bx = qv[k].y, by = qv[k].z, bz = qv[k].w;
            f4 o;
            o.x = rw * bw - rx * bx - ry * by - rz * bz;
            o.y = rw * bx + rx * bw + ry * bz - rz * by;
            o.z = rw * by - rx * bz + ry * bw + rz * bx;
            o.w = rw * bz + rx * by - ry * bx + rz * bw;
            __builtin_nontemporal_store(o, &((f4*)out_quats)[p]);
        }
        __syncthreads();

        // ---- Phase 2: coalesced means store -------------------------------
#pragma unroll
        for (int k = 0; k < 6; ++k) {
            const int gi = mbase_f4 + k * THR + tid;
            if (gi < mf4_lim)
                __builtin_nontemporal_store(((const f4*)s_m)[k * THR + tid],
                                            &((f4*)out_means)[gi]);
        }
    }
}

extern "C" void kernel_launch(void* const* d_in, const int* in_sizes, int n_in,
                              void* d_out, int out_size, void* d_ws, size_t ws_size,
                              hipStream_t stream) {
    const float* trans   = (const float*)d_in[0];
    const float* rotors  = (const float*)d_in[1];
    const float* means   = (const float*)d_in[2];
    const float* quats   = (const float*)d_in[3];
    const int*   indices = (const int*)d_in[4];
    const int M = in_sizes[4];
    float* out = (float*)d_out;

    const int ntiles = (M + PTS - 1) / PTS;
    int blocks = ntiles < 2048 ? ntiles : 2048;
    compose_kernel<<<blocks, THR, 0, stream>>>(trans, rotors, means, quats,
                                               indices, out, M, ntiles);
}